// Round 1
// baseline (73.715 us; speedup 1.0000x reference)
//
#include <hip/hip_runtime.h>

#define Hd 256
#define Ad 64
#define NPSd 48
#define Sd 64
#define Nd (Sd*NPSd)
#define GB 16   // agents per block in v_kernel

// ---------------------------------------------------------------------------
// Kernel A: combo weights.  Wc[h1][h] = sum_a W2[a][h1]*W1[a][h]
//           vb[h] = sum_a b2[a]*W1[a][h]   (bias of v)
//           u[h1] = sum_a W2[a][h1]*b1[a]  (c = t·u + cconst)
//           cconst = b1·b2
// grid = 256 blocks (h1), 256 threads (h)
__global__ __launch_bounds__(256) void combo_kernel(
    const float* __restrict__ W1_w, const float* __restrict__ W1_b,
    const float* __restrict__ W2_w, const float* __restrict__ W2_b,
    float* __restrict__ Wc, float* __restrict__ vb,
    float* __restrict__ u, float* __restrict__ cconst) {
  int h1 = blockIdx.x;
  int h  = threadIdx.x;
  float acc = 0.f;
#pragma unroll 8
  for (int a = 0; a < Ad; ++a)
    acc += W2_w[a*Hd + h1] * W1_w[a*Hd + h];
  Wc[h1*Hd + h] = acc;
  if (h1 == 0) {
    float uu = 0.f, vbb = 0.f;
    for (int a = 0; a < Ad; ++a) {
      uu  += W2_w[a*Hd + h] * W1_b[a];
      vbb += W2_b[a] * W1_w[a*Hd + h];
    }
    u[h]  = uu;
    vb[h] = vbb;
    if (h == 0) {
      float cc = 0.f;
      for (int a = 0; a < Ad; ++a) cc += W1_b[a] * W2_b[a];
      *cconst = cc;
    }
  }
}

// ---------------------------------------------------------------------------
// Kernel B: v[i][:] = t[i]·Wc + vb ;  c[i] = t[i]·u + cconst
// grid = N/GB blocks, 256 threads
__global__ __launch_bounds__(256) void v_kernel(
    const float* __restrict__ temporal,
    const float* __restrict__ Wc, const float* __restrict__ vb,
    const float* __restrict__ u, const float* __restrict__ cconst,
    float* __restrict__ v, float* __restrict__ c) {
  __shared__ float t_lds[GB*Hd];
  __shared__ float u_lds[Hd];
  __shared__ float vb_lds[Hd];
  int tid  = threadIdx.x;
  int base = blockIdx.x * GB;
  for (int k = tid; k < GB*Hd; k += 256)
    t_lds[k] = temporal[(size_t)base*Hd + k];
  u_lds[tid]  = u[tid];
  vb_lds[tid] = vb[tid];
  __syncthreads();

  float acc[GB];
#pragma unroll
  for (int g = 0; g < GB; ++g) acc[g] = 0.f;
  for (int h1 = 0; h1 < Hd; ++h1) {
    float wc = Wc[h1*Hd + tid];          // coalesced over tid
#pragma unroll
    for (int g = 0; g < GB; ++g)
      acc[g] += t_lds[g*Hd + h1] * wc;   // broadcast read
  }
#pragma unroll
  for (int g = 0; g < GB; ++g)
    v[(size_t)(base+g)*Hd + tid] = acc[g] + vb_lds[tid];

  // c[i] = t·u + cconst, one wave per 4 agents
  int wave = tid >> 6, lane = tid & 63;
  float cc0 = *cconst;
  for (int gg = 0; gg < GB/4; ++gg) {
    int g = wave*(GB/4) + gg;
    float p = 0.f;
#pragma unroll
    for (int k = 0; k < Hd/64; ++k)
      p += t_lds[g*Hd + lane + k*64] * u_lds[lane + k*64];
#pragma unroll
    for (int off = 32; off > 0; off >>= 1)
      p += __shfl_down(p, off);
    if (lane == 0) c[base+g] = p + cc0;
  }
}

// ---------------------------------------------------------------------------
// Kernel C: fused score + masked softmax + edge aggregation.
// One block per (scene, agent-row). spatial row staged to LDS once.
__global__ __launch_bounds__(256) void attn_kernel(
    const float* __restrict__ spatial,
    const int* __restrict__ ts_mask,
    const float* __restrict__ v, const float* __restrict__ c,
    float* __restrict__ out) {
  __shared__ float sp_lds[NPSd*Hd];   // 49152 B
  __shared__ float v_lds[Hd];
  __shared__ float num[NPSd];
  __shared__ int   msk[NPSd];

  int row = blockIdx.x;               // 0..N-1
  int s = row / NPSd, i = row - s*NPSd;
  int tid  = threadIdx.x;
  int wave = tid >> 6, lane = tid & 63;

  v_lds[tid] = v[(size_t)row*Hd + tid];
  if (tid < NPSd) msk[tid] = ts_mask[s*NPSd + tid];

  const float4* g4 = (const float4*)(spatial + (size_t)row*NPSd*Hd);
  float4* l4 = (float4*)sp_lds;
#pragma unroll
  for (int k = 0; k < NPSd*Hd/4/256; ++k)
    l4[tid + k*256] = g4[tid + k*256];
  __syncthreads();

  float ne = 0.f;
  for (int j = 0; j < NPSd; ++j) ne += (msk[j] == 1) ? 1.f : 0.f;
  float scale = ne * 0.125f;          // ne / sqrt(A=64)
  float cr = c[row];

  const float4* v4 = (const float4*)v_lds;
  float4 vv = v4[lane];
  for (int j = wave; j < NPSd; j += 4) {
    const float4* r4 = (const float4*)(sp_lds + j*Hd);
    float4 a = r4[lane];
    float p = a.x*vv.x + a.y*vv.y + a.z*vv.z + a.w*vv.w;
#pragma unroll
    for (int off = 32; off > 0; off >>= 1)
      p += __shfl_down(p, off);
    if (lane == 0) {
      bool valid = (msk[i] == 1) && (msk[j] == 1) && (j != i);
      num[j] = valid ? __expf((p + cr) * scale) : 0.f;
    }
  }
  __syncthreads();

  float den = 0.f, o = 0.f;
  for (int j = 0; j < NPSd; ++j) {
    float nj = num[j];                 // broadcast
    den += nj;
    o   += nj * sp_lds[j*Hd + tid];    // stride-1 across lanes
  }
  float inv = den > 0.f ? 1.f/den : 0.f;
  out[(size_t)row*Hd + tid] = o * inv;
}

// ---------------------------------------------------------------------------
extern "C" void kernel_launch(void* const* d_in, const int* in_sizes, int n_in,
                              void* d_out, int out_size, void* d_ws, size_t ws_size,
                              hipStream_t stream) {
  const float* spatial  = (const float*)d_in[0];
  const float* temporal = (const float*)d_in[1];
  const float* W1_w     = (const float*)d_in[2];
  const float* W1_b     = (const float*)d_in[3];
  const float* W2_w     = (const float*)d_in[4];
  const float* W2_b     = (const float*)d_in[5];
  const int*   ts_mask  = (const int*)d_in[6];
  float* out = (float*)d_out;

  float* ws = (float*)d_ws;
  float* v      = ws;                  // N*H
  float* c      = v  + (size_t)Nd*Hd;  // N
  float* Wc     = c  + Nd;             // H*H
  float* vb     = Wc + Hd*Hd;          // H
  float* u      = vb + Hd;             // H
  float* cconst = u  + Hd;             // 1

  combo_kernel<<<Hd, Hd, 0, stream>>>(W1_w, W1_b, W2_w, W2_b, Wc, vb, u, cconst);
  v_kernel<<<Nd/GB, 256, 0, stream>>>(temporal, Wc, vb, u, cconst, v, c);
  attn_kernel<<<Nd, 256, 0, stream>>>(spatial, ts_mask, v, c, out);
}